// Round 2
// baseline (640.025 us; speedup 1.0000x reference)
//
#include <hip/hip_runtime.h>
#include <hip/hip_bf16.h>

// Problem constants
#define B_   2
#define C_   64
#define D_   32
#define H_   96
#define W_   96
#define QK_  32
#define TW_  8
#define HW_  (H_*W_)          // 9216
#define DHW_ (D_*H_*W_)       // 294912
#define TDIM_ 256

// ws layout (floats): [0:32) qb = bq + text_bias, [32:64) kb = bk + text_bias
__global__ void prep_kernel(const float* __restrict__ te,
                            const float* __restrict__ wt,
                            const float* __restrict__ bt,
                            const float* __restrict__ bq,
                            const float* __restrict__ bk,
                            float* __restrict__ ws) {
    __shared__ float tm[TDIM_];
    const int t = threadIdx.x;
    float s = 0.f;
    #pragma unroll
    for (int tok = 0; tok < 32; ++tok) s += te[tok*TDIM_ + t];
    tm[t] = s * (1.0f/32.0f);
    __syncthreads();
    if (t < QK_) {
        float acc = bt[t];
        for (int c = 0; c < TDIM_; ++c) acc += wt[t*TDIM_ + c] * tm[c];
        ws[t]       = bq[t] + acc;
        ws[QK_ + t] = bk[t] + acc;
    }
}

// LDS: xs [c][w][e] bf16, stride 32 along e  -> 64*8*32*2 = 32768 B
//      Kb [w][q][e] bf16, w-stride 1032 elems (pad: conflict-free b128) = 16512 B
//      total 49280 B -> 3 blocks/CU
#define KB_WSTRIDE 1032

__global__ __launch_bounds__(256, 3)
void attn_main(const float* __restrict__ x,
               const float* __restrict__ wq,
               const float* __restrict__ wk,
               const float* __restrict__ wv,
               const float* __restrict__ bv,
               const float* __restrict__ pos,
               const float* __restrict__ gm,
               const float* __restrict__ ws,
               float* __restrict__ out) {
    __shared__ __align__(16) __hip_bfloat16 xs[C_*TW_*D_];
    __shared__ __align__(16) __hip_bfloat16 Kb[TW_*KB_WSTRIDE];

    const float* qb    = ws;
    const float* kbias = ws + QK_;

    const int tid = threadIdx.x;
    const int d   = tid >> 3;   // 0..31  depth slice this thread owns
    const int w   = tid & 7;    // 0..7   column within tile
    const int bx  = blockIdx.x;
    const int wt  = bx % (W_/TW_);
    const int h   = (bx / (W_/TW_)) % H_;
    const int b   = bx / ((W_/TW_) * H_);

    const int base = b*(C_*DHW_) + d*HW_ + h*W_ + wt*TW_ + w;

    // ---- Phase 0: load own x column (fp32), mirror to LDS as bf16 ----
    float xv[C_];
    #pragma unroll
    for (int c = 0; c < C_; ++c) {
        float v = x[base + c*DHW_];
        xv[c] = v;
        xs[c*(TW_*D_) + w*D_ + d] = __float2bfloat16(v);
    }

    // ---- Phase 1: K -> LDS (bf16), Q -> regs (fp32) ----
    #pragma unroll 2
    for (int q = 0; q < QK_; ++q) {
        float a = kbias[q] + pos[q*D_ + d];
        #pragma unroll
        for (int c = 0; c < C_; ++c) a += wk[q*C_ + c] * xv[c];
        Kb[w*KB_WSTRIDE + q*D_ + d] = __float2bfloat16(a);
    }
    float Qr[QK_];
    #pragma unroll 2
    for (int q = 0; q < QK_; ++q) {
        float a = qb[q] + pos[q*D_ + d];
        #pragma unroll
        for (int c = 0; c < C_; ++c) a += wq[q*C_ + c] * xv[c];
        Qr[q] = a;
    }
    __syncthreads();

    // ---- Phase 2: scores S[e] = sum_q Q[q, my d] * K[q, e] ----
    float S[D_];
    #pragma unroll
    for (int e = 0; e < D_; ++e) S[e] = 0.f;
    #pragma unroll 4
    for (int q = 0; q < QK_; ++q) {
        const float qv = Qr[q];
        const uint4* kr = reinterpret_cast<const uint4*>(Kb + w*KB_WSTRIDE + q*D_);
        #pragma unroll
        for (int j = 0; j < 4; ++j) {
            uint4 u = kr[j];
            S[8*j+0] += qv * __uint_as_float(u.x << 16);
            S[8*j+1] += qv * __uint_as_float(u.x & 0xffff0000u);
            S[8*j+2] += qv * __uint_as_float(u.y << 16);
            S[8*j+3] += qv * __uint_as_float(u.y & 0xffff0000u);
            S[8*j+4] += qv * __uint_as_float(u.z << 16);
            S[8*j+5] += qv * __uint_as_float(u.z & 0xffff0000u);
            S[8*j+6] += qv * __uint_as_float(u.w << 16);
            S[8*j+7] += qv * __uint_as_float(u.w & 0xffff0000u);
        }
    }

    // ---- softmax over e (scores / sqrt(32)) ----
    const float rsc = 0.17677669529663687f;  // 1/sqrt(32)
    float m = -1e30f;
    #pragma unroll
    for (int e = 0; e < D_; ++e) { S[e] *= rsc; m = fmaxf(m, S[e]); }
    float sum = 0.f;
    #pragma unroll
    for (int e = 0; e < D_; ++e) { float p = __expf(S[e] - m); S[e] = p; sum += p; }
    const float rs = 1.0f / sum;
    #pragma unroll
    for (int e = 0; e < D_; ++e) S[e] *= rs;

    // ---- Phase 3: A[c'] = sum_e attn[e] * x[c', e] (x from LDS bf16) ----
    float A[C_];
    #pragma unroll 8
    for (int c = 0; c < C_; ++c) {
        const uint4* xr = reinterpret_cast<const uint4*>(xs + c*(TW_*D_) + w*D_);
        float a = 0.f;
        #pragma unroll
        for (int j = 0; j < 4; ++j) {
            uint4 u = xr[j];
            a += S[8*j+0] * __uint_as_float(u.x << 16);
            a += S[8*j+1] * __uint_as_float(u.x & 0xffff0000u);
            a += S[8*j+2] * __uint_as_float(u.y << 16);
            a += S[8*j+3] * __uint_as_float(u.y & 0xffff0000u);
            a += S[8*j+4] * __uint_as_float(u.z << 16);
            a += S[8*j+5] * __uint_as_float(u.z & 0xffff0000u);
            a += S[8*j+6] * __uint_as_float(u.w << 16);
            a += S[8*j+7] * __uint_as_float(u.w & 0xffff0000u);
        }
        A[c] = a;
    }

    // ---- Phase 4: out[c] = sigmoid(g)*(bv[c] + wv[c,:]@A) + (1-g)*x ----
    // (sum_e attn = 1 folds bv straight through the attention average)
    const float g  = 1.0f / (1.0f + __expf(-gm[0]));
    const float gi = 1.0f - g;
    #pragma unroll 2
    for (int c = 0; c < C_; ++c) {
        float a = bv[c];
        #pragma unroll
        for (int cp = 0; cp < C_; ++cp) a += wv[c*C_ + cp] * A[cp];
        const float r = __bfloat162float(xs[c*(TW_*D_) + w*D_ + d]);
        out[base + c*DHW_] = g*a + gi*r;
    }
}

extern "C" void kernel_launch(void* const* d_in, const int* in_sizes, int n_in,
                              void* d_out, int out_size, void* d_ws, size_t ws_size,
                              hipStream_t stream) {
    const float* x     = (const float*)d_in[0];
    const float* te    = (const float*)d_in[1];
    const float* wq    = (const float*)d_in[2];
    const float* bq    = (const float*)d_in[3];
    const float* wk    = (const float*)d_in[4];
    const float* bk    = (const float*)d_in[5];
    const float* wv    = (const float*)d_in[6];
    const float* bv    = (const float*)d_in[7];
    const float* wt    = (const float*)d_in[8];
    const float* bt    = (const float*)d_in[9];
    const float* pos   = (const float*)d_in[10];
    const float* gamma = (const float*)d_in[11];
    float* out = (float*)d_out;
    float* ws  = (float*)d_ws;

    prep_kernel<<<1, 256, 0, stream>>>(te, wt, bt, bq, bk, ws);

    const int nblk = B_ * H_ * (W_/TW_);   // 2304
    attn_main<<<nblk, 256, 0, stream>>>(x, wq, wk, wv, bv, pos, gamma, ws, out);
}

// Round 3
// 482.048 us; speedup vs baseline: 1.3277x; 1.3277x over previous
//
#include <hip/hip_runtime.h>
#include <hip/hip_bf16.h>

// Problem constants
#define B_   2
#define C_   64
#define D_   32
#define H_   96
#define W_   96
#define QK_  32
#define TW_  8
#define HW_  (H_*W_)          // 9216
#define DHW_ (D_*H_*W_)       // 294912
#define TDIM_ 256

// ws layout: floats [0,1024) PB[q][d]=bq+tb+pos, [1024,2048) KB2[q][d]=bk+tb+pos
// uints  [2048,3072) wqp (32q x 32 c-pairs), [3072,4096) wkp, [4096,6144) wvp (64 x 32)
#define WS_PB   0
#define WS_KB2  1024
#define WS_WQP  2048
#define WS_WKP  3072
#define WS_WVP  4096

__device__ __forceinline__ float dot2bf(uint a, uint b, float c) {
    float d;
    asm("v_dot2_f32_bf16 %0, %1, %2, %3" : "=v"(d) : "v"(a), "v"(b), "v"(c));
    return d;
}

__device__ __forceinline__ uint packbf2(float lo, float hi) {
    uint a = (uint)__bfloat16_as_ushort(__float2bfloat16(lo));
    uint b = (uint)__bfloat16_as_ushort(__float2bfloat16(hi));
    return a | (b << 16);
}

__global__ void prep_kernel(const float* __restrict__ te,
                            const float* __restrict__ wt,
                            const float* __restrict__ bt,
                            const float* __restrict__ bq,
                            const float* __restrict__ bk,
                            const float* __restrict__ wq,
                            const float* __restrict__ wk,
                            const float* __restrict__ wv,
                            const float* __restrict__ pos,
                            float* __restrict__ ws) {
    __shared__ float tm[TDIM_];
    __shared__ float qtb[QK_], ktb[QK_];
    const int t = threadIdx.x;
    float s = 0.f;
    #pragma unroll
    for (int tok = 0; tok < 32; ++tok) s += te[tok*TDIM_ + t];
    tm[t] = s * (1.0f/32.0f);
    __syncthreads();
    if (t < QK_) {
        float acc = bt[t];
        for (int c = 0; c < TDIM_; ++c) acc += wt[t*TDIM_ + c] * tm[c];
        qtb[t] = bq[t] + acc;
        ktb[t] = bk[t] + acc;
    }
    __syncthreads();
    // PB / KB2 tables (1024 each): i = q*32 + d
    for (int i = t; i < 1024; i += TDIM_) {
        int q = i >> 5, d = i & 31;
        ws[WS_PB  + i] = qtb[q] + pos[q*32 + d];
        ws[WS_KB2 + i] = ktb[q] + pos[q*32 + d];
    }
    uint* wsu = reinterpret_cast<uint*>(ws);
    for (int i = t; i < 1024; i += TDIM_) {  // wq: 32 q x 32 pairs
        int q = i >> 5, cp = i & 31;
        wsu[WS_WQP + i] = packbf2(wq[q*64 + 2*cp], wq[q*64 + 2*cp + 1]);
    }
    for (int i = t; i < 1024; i += TDIM_) {
        int q = i >> 5, cp = i & 31;
        wsu[WS_WKP + i] = packbf2(wk[q*64 + 2*cp], wk[q*64 + 2*cp + 1]);
    }
    for (int i = t; i < 2048; i += TDIM_) {  // wv: 64 c x 32 pairs
        int c = i >> 5, cp = i & 31;
        wsu[WS_WVP + i] = packbf2(wv[c*64 + 2*cp], wv[c*64 + 2*cp + 1]);
    }
}

// LDS (uints):
//  xs: 64 c x 128 dwords  (per c: 8 w x 16 e-pair dwords, XOR-swizzled)   = 32768 B
//  kb: 8 w x 32 e x 16 q-pair dwords (XOR-swizzled)                        = 16384 B
// total 49152 B -> 3 blocks/CU
__global__ __launch_bounds__(256, 3)
void attn_main(const float* __restrict__ x,
               const float* __restrict__ bv,
               const float* __restrict__ gm,
               const float* __restrict__ ws,
               float* __restrict__ out) {
    __shared__ uint xs_u[64*128];
    __shared__ uint kb_u[8*512];

    const float* PB  = ws + WS_PB;
    const float* KB2 = ws + WS_KB2;
    const uint*  wsu = reinterpret_cast<const uint*>(ws);
    const uint*  wqp = wsu + WS_WQP;
    const uint*  wkp = wsu + WS_WKP;
    const uint*  wvp = wsu + WS_WVP;

    const int tid = threadIdx.x;
    const int d   = tid >> 3;   // 0..31 depth slice owned
    const int w   = tid & 7;    // 0..7  column within tile

    // XCD pair swizzle: bx = G*16 + s*8 + r ; partners (s=0,1) share 64B lines
    // and share XCD (bx % 8 == r).
    const int bx = blockIdx.x;
    const int G  = bx >> 4;
    const int r  = bx & 7;
    const int sP = (bx >> 3) & 1;
    const int wp = G % 6;
    const int hh = (G / 6) % 12;
    const int b  = G / 72;
    const int h  = hh*8 + r;
    const int wtile = wp*2 + sP;

    const int base = b*(C_*DHW_) + d*HW_ + h*W_ + wtile*TW_ + w;
    const int swx  = (w >> 1) & 3;

    // ---- Phase 0: load own x column; pack bf16 pairs (regs) + scatter to xs ----
    uint xp[32];
    {
        // half-index within a c-row of xs (ushort view), from (w,d) swizzle
        const int slot0 = ((d >> 3) ^ swx) & 3;
        const int hbase = ((w*16 + (slot0 << 2) + ((d >> 1) & 3)) << 1) | (d & 1);
        ushort* xs_h = reinterpret_cast<ushort*>(xs_u);
        #pragma unroll
        for (int cp = 0; cp < 32; ++cp) {
            float v0 = x[base + (2*cp)*DHW_];
            float v1 = x[base + (2*cp+1)*DHW_];
            uint p0 = packbf2(v0, v1);
            xp[cp] = p0;
            xs_h[(2*cp)*256 + hbase]   = (ushort)(p0 & 0xffffu);
            xs_h[(2*cp+1)*256 + hbase] = (ushort)(p0 >> 16);
        }
    }

    // ---- Phase 1: Q (regs, packed) and K (LDS, packed), dot2 over c-pairs ----
    uint Qp[16], kp[16];
    #pragma unroll 2
    for (int qh = 0; qh < 16; ++qh) {
        const int q0 = 2*qh, q1 = 2*qh + 1;
        float aQ0 = PB[q0*32 + d],  aQ1 = PB[q1*32 + d];
        float aK0 = KB2[q0*32 + d], aK1 = KB2[q1*32 + d];
        const uint* wq0 = wqp + q0*32; const uint* wq1 = wqp + q1*32;
        const uint* wk0 = wkp + q0*32; const uint* wk1 = wkp + q1*32;
        #pragma unroll
        for (int cp = 0; cp < 32; ++cp) {
            uint xv = xp[cp];
            aQ0 = dot2bf(wq0[cp], xv, aQ0);
            aQ1 = dot2bf(wq1[cp], xv, aQ1);
            aK0 = dot2bf(wk0[cp], xv, aK0);
            aK1 = dot2bf(wk1[cp], xv, aK1);
        }
        Qp[qh] = packbf2(aQ0, aQ1);
        kp[qh] = packbf2(aK0, aK1);
    }
    // write K row (w, e=d): 4x b128, swizzled slots
    {
        uint* kw = kb_u + w*512 + d*16;
        const int swk = swx ^ ((d >> 1) & 3);
        #pragma unroll
        for (int g = 0; g < 4; ++g) {
            uint4 v = make_uint4(kp[4*g+0], kp[4*g+1], kp[4*g+2], kp[4*g+3]);
            *reinterpret_cast<uint4*>(kw + (((g ^ swk) & 3) << 2)) = v;
        }
    }
    __syncthreads();

    // ---- Phase 2: S[e] = sum_q Q[q,d] K[q,e] via dot2 over q-pairs ----
    float S[D_];
    #pragma unroll 2
    for (int e = 0; e < D_; ++e) {
        const uint* kr = kb_u + w*512 + e*16;
        const int swk = swx ^ ((e >> 1) & 3);
        float acc = 0.f;
        #pragma unroll
        for (int g = 0; g < 4; ++g) {
            uint4 kv = *reinterpret_cast<const uint4*>(kr + (((g ^ swk) & 3) << 2));
            acc = dot2bf(Qp[4*g+0], kv.x, acc);
            acc = dot2bf(Qp[4*g+1], kv.y, acc);
            acc = dot2bf(Qp[4*g+2], kv.z, acc);
            acc = dot2bf(Qp[4*g+3], kv.w, acc);
        }
        S[e] = acc;
    }

    // ---- softmax over e ----
    const float rsc = 0.17677669529663687f;  // 1/sqrt(32)
    float m = -1e30f;
    #pragma unroll
    for (int e = 0; e < D_; ++e) { S[e] *= rsc; m = fmaxf(m, S[e]); }
    float sum = 0.f;
    #pragma unroll
    for (int e = 0; e < D_; ++e) { float p = __expf(S[e] - m); S[e] = p; sum += p; }
    const float rs = 1.0f / sum;
    uint ap[16];
    #pragma unroll
    for (int ep = 0; ep < 16; ++ep) ap[ep] = packbf2(S[2*ep]*rs, S[2*ep+1]*rs);

    // ---- Phase 3: A[c] = sum_e attn[e] x[c,e]; pack pairs along c ----
    uint Ap[32];
    #pragma unroll 2
    for (int ch = 0; ch < 32; ++ch) {
        float a0 = 0.f, a1 = 0.f;
        const uint* xr0 = xs_u + (2*ch)*128 + w*16;
        const uint* xr1 = xr0 + 128;
        #pragma unroll
        for (int g = 0; g < 4; ++g) {
            const int off = (((g ^ swx) & 3) << 2);
            uint4 u0 = *reinterpret_cast<const uint4*>(xr0 + off);
            uint4 u1 = *reinterpret_cast<const uint4*>(xr1 + off);
            a0 = dot2bf(ap[4*g+0], u0.x, a0);
            a0 = dot2bf(ap[4*g+1], u0.y, a0);
            a0 = dot2bf(ap[4*g+2], u0.z, a0);
            a0 = dot2bf(ap[4*g+3], u0.w, a0);
            a1 = dot2bf(ap[4*g+0], u1.x, a1);
            a1 = dot2bf(ap[4*g+1], u1.y, a1);
            a1 = dot2bf(ap[4*g+2], u1.z, a1);
            a1 = dot2bf(ap[4*g+3], u1.w, a1);
        }
        Ap[ch] = packbf2(a0, a1);
    }

    // ---- Phase 4: out[c] = g*(bv[c] + wv[c,:]@A) + (1-g)*x ----
    const float gv = 1.0f / (1.0f + __expf(-gm[0]));
    const float gi = 1.0f - gv;
    #pragma unroll 2
    for (int c = 0; c < C_; ++c) {
        float acc = bv[c];
        const uint* row = wvp + c*32;
        #pragma unroll
        for (int cp = 0; cp < 32; ++cp) acc = dot2bf(row[cp], Ap[cp], acc);
        uint xu = xp[c >> 1];
        float xres = __uint_as_float((c & 1) ? (xu & 0xffff0000u) : (xu << 16));
        out[base + c*DHW_] = gv*acc + gi*xres;
    }
}

extern "C" void kernel_launch(void* const* d_in, const int* in_sizes, int n_in,
                              void* d_out, int out_size, void* d_ws, size_t ws_size,
                              hipStream_t stream) {
    const float* x     = (const float*)d_in[0];
    const float* te    = (const float*)d_in[1];
    const float* wq    = (const float*)d_in[2];
    const float* bq    = (const float*)d_in[3];
    const float* wk    = (const float*)d_in[4];
    const float* bk    = (const float*)d_in[5];
    const float* wv    = (const float*)d_in[6];
    const float* bv    = (const float*)d_in[7];
    const float* wt    = (const float*)d_in[8];
    const float* bt    = (const float*)d_in[9];
    const float* pos   = (const float*)d_in[10];
    const float* gamma = (const float*)d_in[11];
    float* out = (float*)d_out;
    float* ws  = (float*)d_ws;

    prep_kernel<<<1, 256, 0, stream>>>(te, wt, bt, bq, bk, wq, wk, wv, pos, ws);

    const int nblk = B_ * H_ * (W_/TW_);   // 2304 = 144 groups * 16
    attn_main<<<nblk, 256, 0, stream>>>(x, bv, gamma, ws, out);
}